// Round 1
// baseline (1115.418 us; speedup 1.0000x reference)
//
#include <hip/hip_runtime.h>

typedef __bf16 bf16x8 __attribute__((ext_vector_type(8)));
typedef float f32x4 __attribute__((ext_vector_type(4)));

#define L2E 1.4426950408889634f

// ---------------------------------------------------------------------------
// Fused conv1(5x5,s2)+ReLU -> conv2(3x3,s2)+ReLU per image. One block/image.
// img [3][40][40] -> c1 [16][18][18] -> flat out [2048] (=[32][8][8])
// ---------------------------------------------------------------------------
__global__ __launch_bounds__(256, 2) void conv_fused(
    const float* __restrict__ img, const float* __restrict__ w1, const float* __restrict__ b1,
    const float* __restrict__ w2, const float* __restrict__ b2, float* __restrict__ flat) {
  __shared__ float simg[4800];      // 3*40*40, reused as sc2[2048] later
  __shared__ float sc1[5184];       // 16*18*18
  __shared__ float sw1[1200];       // 16*75
  __shared__ float sw2[32 * 145];   // padded stride 145 (bank spread)
  __shared__ float sb1[16];
  __shared__ float sb2[32];
  const int n = blockIdx.x;
  const int t = threadIdx.x;
  const float* ib = img + (size_t)n * 4800;
  for (int i = t; i < 4800; i += 256) simg[i] = ib[i];
  for (int i = t; i < 1200; i += 256) sw1[i] = w1[i];
  for (int i = t; i < 4608; i += 256) {
    const int oc = i / 144, rem = i - oc * 144;
    sw2[oc * 145 + rem] = w2[i];
  }
  if (t < 16) sb1[t] = b1[t];
  else if (t < 48) sb2[t - 16] = b2[t - 16];
  __syncthreads();

  // ---- conv1: thread -> oc = t&15, 2x2 output quads over 9x9 quad grid ----
  {
    const int oc = t & 15;
    float wr[75];
#pragma unroll
    for (int i = 0; i < 75; ++i) wr[i] = sw1[oc * 75 + i];
    const float bias = sb1[oc];
#pragma unroll 1
    for (int q = (t >> 4); q < 81; q += 16) {
      const int qy = q / 9, qx = q - qy * 9;
      float a00 = bias, a01 = bias, a10 = bias, a11 = bias;
#pragma unroll
      for (int ic = 0; ic < 3; ++ic) {
        float rg[7][7];
        const int base = ic * 1600 + qy * 160 + qx * 4;
#pragma unroll
        for (int row = 0; row < 7; ++row) {
          const float* rp = &simg[base + row * 40];
          const float2 v0 = *(const float2*)(rp);
          const float2 v1 = *(const float2*)(rp + 2);
          const float2 v2 = *(const float2*)(rp + 4);
          rg[row][0] = v0.x; rg[row][1] = v0.y; rg[row][2] = v1.x; rg[row][3] = v1.y;
          rg[row][4] = v2.x; rg[row][5] = v2.y; rg[row][6] = rp[6];
        }
#pragma unroll
        for (int ky = 0; ky < 5; ++ky)
#pragma unroll
          for (int kx = 0; kx < 5; ++kx) {
            const float wv = wr[ic * 25 + ky * 5 + kx];
            a00 = fmaf(rg[ky][kx], wv, a00);
            a01 = fmaf(rg[ky][kx + 2], wv, a01);
            a10 = fmaf(rg[ky + 2][kx], wv, a10);
            a11 = fmaf(rg[ky + 2][kx + 2], wv, a11);
          }
      }
      const int o = oc * 324 + qy * 36 + qx * 2;  // (2qy)*18 + 2qx
      sc1[o] = fmaxf(a00, 0.f);
      sc1[o + 1] = fmaxf(a01, 0.f);
      sc1[o + 18] = fmaxf(a10, 0.f);
      sc1[o + 19] = fmaxf(a11, 0.f);
    }
  }
  __syncthreads();

  // ---- conv2: thread -> oc = t&31, 2x2 quads over 4x4 quad grid ----
  float* sc2 = simg;  // reuse (simg dead)
  {
    const int oc = t & 31;
    float wr[144];
#pragma unroll
    for (int i = 0; i < 144; ++i) wr[i] = sw2[oc * 145 + i];
    const float bias = sb2[oc];
#pragma unroll 1
    for (int q = (t >> 5); q < 16; q += 8) {
      const int qy = q >> 2, qx = q & 3;
      float a00 = bias, a01 = bias, a10 = bias, a11 = bias;
#pragma unroll
      for (int ic = 0; ic < 16; ++ic) {
        float rg[5][5];
        const int base = ic * 324 + qy * 72 + qx * 4;  // (4qy)*18 + 4qx
#pragma unroll
        for (int row = 0; row < 5; ++row) {
          const float* rp = &sc1[base + row * 18];
          const float2 v0 = *(const float2*)(rp);
          const float2 v1 = *(const float2*)(rp + 2);
          rg[row][0] = v0.x; rg[row][1] = v0.y; rg[row][2] = v1.x; rg[row][3] = v1.y;
          rg[row][4] = rp[4];
        }
#pragma unroll
        for (int ky = 0; ky < 3; ++ky)
#pragma unroll
          for (int kx = 0; kx < 3; ++kx) {
            const float wv = wr[ic * 9 + ky * 3 + kx];
            a00 = fmaf(rg[ky][kx], wv, a00);
            a01 = fmaf(rg[ky][kx + 2], wv, a01);
            a10 = fmaf(rg[ky + 2][kx], wv, a10);
            a11 = fmaf(rg[ky + 2][kx + 2], wv, a11);
          }
      }
      const int o = oc * 64 + qy * 16 + qx * 2;  // (2qy)*8 + 2qx
      sc2[o] = fmaxf(a00, 0.f);
      sc2[o + 1] = fmaxf(a01, 0.f);
      sc2[o + 8] = fmaxf(a10, 0.f);
      sc2[o + 9] = fmaxf(a11, 0.f);
    }
  }
  __syncthreads();
  float* ob = flat + (size_t)n * 2048;
  for (int i = t; i < 2048; i += 256) ob[i] = sc2[i];
}

// ---------------------------------------------------------------------------
// Generic fp32 GEMM: C[m][n] = epi(sum_k A[m*lda+k]*W[n*ldw+k] + bias[n])
// tile 32(M) x 128(N), K-step 32. grid = (M/32, N/128), block 256.
// EPI: 0 none, 1 relu
// ---------------------------------------------------------------------------
template <int EPI>
__global__ __launch_bounds__(256) void gemm_nt(
    const float* __restrict__ A, const float* __restrict__ W, const float* __restrict__ bias,
    float* __restrict__ C, int M, int N, int K, int lda, int ldw, int ldc) {
  __shared__ float As[32][36];
  __shared__ float Ws[32][132];
  const int t = threadIdx.x;
  const int m0 = blockIdx.x * 32, n0 = blockIdx.y * 128;
  const int ty = t >> 6, tx = t & 63;
  float acc[8][2];
#pragma unroll
  for (int i = 0; i < 8; ++i) { acc[i][0] = 0.f; acc[i][1] = 0.f; }
  const int arow = t >> 3, akc = (t & 7) * 4;
  const int wrow = t >> 1, wkh = (t & 1) * 16;
  for (int k0 = 0; k0 < K; k0 += 32) {
    float4 av = {0.f, 0.f, 0.f, 0.f};
    if (k0 + akc < K)
      av = *reinterpret_cast<const float4*>(&A[(size_t)(m0 + arow) * lda + k0 + akc]);
    float4 wv[4];
#pragma unroll
    for (int j = 0; j < 4; ++j) {
      wv[j] = {0.f, 0.f, 0.f, 0.f};
      if (k0 + wkh + 4 * j < K)
        wv[j] = *reinterpret_cast<const float4*>(&W[(size_t)(n0 + wrow) * ldw + k0 + wkh + 4 * j]);
    }
    __syncthreads();  // prev compute done before overwriting LDS
    As[akc + 0][arow] = av.x; As[akc + 1][arow] = av.y;
    As[akc + 2][arow] = av.z; As[akc + 3][arow] = av.w;
#pragma unroll
    for (int j = 0; j < 4; ++j) {
      Ws[wkh + 4 * j + 0][wrow] = wv[j].x; Ws[wkh + 4 * j + 1][wrow] = wv[j].y;
      Ws[wkh + 4 * j + 2][wrow] = wv[j].z; Ws[wkh + 4 * j + 3][wrow] = wv[j].w;
    }
    __syncthreads();
#pragma unroll
    for (int kk = 0; kk < 32; ++kk) {
      const float4 a0 = *reinterpret_cast<const float4*>(&As[kk][ty * 8]);
      const float4 a1 = *reinterpret_cast<const float4*>(&As[kk][ty * 8 + 4]);
      const float2 b = *reinterpret_cast<const float2*>(&Ws[kk][tx * 2]);
      float ar[8];
      ar[0] = a0.x; ar[1] = a0.y; ar[2] = a0.z; ar[3] = a0.w;
      ar[4] = a1.x; ar[5] = a1.y; ar[6] = a1.z; ar[7] = a1.w;
#pragma unroll
      for (int i = 0; i < 8; ++i) {
        acc[i][0] = fmaf(ar[i], b.x, acc[i][0]);
        acc[i][1] = fmaf(ar[i], b.y, acc[i][1]);
      }
    }
  }
  const float b0 = bias[n0 + tx * 2], b1 = bias[n0 + tx * 2 + 1];
#pragma unroll
  for (int i = 0; i < 8; ++i) {
    float r0 = acc[i][0] + b0, r1 = acc[i][1] + b1;
    if (EPI == 1) { r0 = fmaxf(r0, 0.f); r1 = fmaxf(r1, 0.f); }
    float2 o; o.x = r0; o.y = r1;
    *reinterpret_cast<float2*>(&C[(size_t)(m0 + ty * 8 + i) * ldc + n0 + tx * 2]) = o;
  }
}

// ---------------------------------------------------------------------------
__global__ void embed_fill(const int* __restrict__ cid, const float* __restrict__ emb,
                           float* __restrict__ feat) {
  const int id = blockIdx.x * 256 + threadIdx.x;  // 8192*16
  const int n = id >> 4, e = id & 15;
  feat[n * 144 + 128 + e] = emb[cid[n] * 16 + e];
}

__global__ void gru_gates(const float* __restrict__ gi, const float* __restrict__ gh,
                          const float* __restrict__ h, float* __restrict__ nh) {
  const int id = blockIdx.x * 256 + threadIdx.x;  // 8192*128
  const int n = id >> 7, j = id & 127;
  const int b = n * 384 + j;
  const float r = 1.f / (1.f + __expf(-(gi[b] + gh[b])));
  const float z = 1.f / (1.f + __expf(-(gi[b + 128] + gh[b + 128])));
  const float nn = tanhf(gi[b + 256] + r * gh[b + 256]);
  nh[id] = (1.f - z) * nn + z * h[id];
}

// Qf,Kf,Vf fp32 [8192][128] -> Qb (scaled) bf16, Kb bf16 row-major, Vt bf16 [128][8192]
__global__ __launch_bounds__(256) void pack_qkv(
    const float* __restrict__ Qf, const float* __restrict__ Kf, const float* __restrict__ Vf,
    __bf16* __restrict__ Qb, __bf16* __restrict__ Kb, __bf16* __restrict__ Vt) {
  __shared__ float sv[64][132];
  const int t = threadIdx.x;
  const int m0 = blockIdx.x * 64;
  for (int i = t; i < 8192; i += 256) {
    const int mm = i >> 7, c = i & 127;
    const int g = (m0 + mm) * 128 + c;
    Qb[g] = (__bf16)(Qf[g] * 0.08838834764831845f);  // 1/sqrt(128)
    Kb[g] = (__bf16)Kf[g];
    sv[mm][c] = Vf[g];
  }
  __syncthreads();
  const int d = t >> 1, mh = (t & 1) * 32;
#pragma unroll
  for (int g8 = 0; g8 < 4; ++g8) {
    bf16x8 v;
#pragma unroll
    for (int j = 0; j < 8; ++j) v[j] = (__bf16)sv[mh + g8 * 8 + j][d];
    *reinterpret_cast<bf16x8*>(&Vt[(size_t)d * 8192 + m0 + mh + g8 * 8]) = v;
  }
}

// ---------------------------------------------------------------------------
// Flash attention, bf16 MFMA 16x16x32. Block = 4 waves, 64 q rows.
// grid (128 qblocks, 4 j-splits). Partials: Opart (unnormalized), Marr, Larr.
// ---------------------------------------------------------------------------
__global__ __launch_bounds__(256, 2) void flash_attn(
    const __bf16* __restrict__ Qb, const __bf16* __restrict__ Kb, const __bf16* __restrict__ Vt,
    const int* __restrict__ adj, float* __restrict__ Opart,
    float* __restrict__ Marr, float* __restrict__ Larr) {
  __shared__ __bf16 Klds[64 * 128];   // [j][k], xor-swizzled 16B chunks
  __shared__ __bf16 Vlds[128 * 64];   // [d][j], xor-swizzled
  __shared__ __bf16 Plds[4][16 * 72]; // per-wave P tile, row stride 72
  const int t = threadIdx.x;
  const int w = t >> 6, l = t & 63;
  const int lr = l & 15, lg = l >> 4;
  const int qbase = blockIdx.x * 64 + w * 16;
  const int split = blockIdx.y;

  bf16x8 qf[4];
#pragma unroll
  for (int kk = 0; kk < 4; ++kk)
    qf[kk] = *reinterpret_cast<const bf16x8*>(&Qb[(qbase + lr) * 128 + kk * 32 + lg * 8]);

  f32x4 accO[8];
#pragma unroll
  for (int n = 0; n < 8; ++n) accO[n] = f32x4{0.f, 0.f, 0.f, 0.f};
  float mrow[4] = {-1e9f, -1e9f, -1e9f, -1e9f};
  float lrow[4] = {0.f, 0.f, 0.f, 0.f};

  const int j0 = split * 2048, j1 = j0 + 2048;
  for (int jt = j0; jt < j1; jt += 64) {
    // stage K (64x128) and V (128x64) tiles, swizzle chunk ^= row&7
#pragma unroll
    for (int i = 0; i < 4; ++i) {
      const int idx = i * 256 + t;
      {
        const int row = idx >> 4, c = idx & 15;
        const uint4 v = *reinterpret_cast<const uint4*>(&Kb[(size_t)(jt + row) * 128 + c * 8]);
        *reinterpret_cast<uint4*>(&Klds[row * 128 + ((c ^ (row & 7)) * 8)]) = v;
      }
      {
        const int d = idx >> 3, c = idx & 7;
        const uint4 v = *reinterpret_cast<const uint4*>(&Vt[(size_t)d * 8192 + jt + c * 8]);
        *reinterpret_cast<uint4*>(&Vlds[d * 64 + ((c ^ (d & 7)) * 8)]) = v;
      }
    }
    __syncthreads();

    // S = Q K^T  (rows=q via C-layout, cols=j)
    f32x4 sacc[4];
#pragma unroll
    for (int st = 0; st < 4; ++st) {
      f32x4 a = f32x4{0.f, 0.f, 0.f, 0.f};
      const int jl = st * 16 + lr;
#pragma unroll
      for (int kk = 0; kk < 4; ++kk) {
        const bf16x8 kf = *reinterpret_cast<const bf16x8*>(
            &Klds[jl * 128 + (((kk * 4 + lg) ^ (jl & 7)) * 8)]);
        a = __builtin_amdgcn_mfma_f32_16x16x32_bf16(qf[kk], kf, a, 0, 0, 0);
      }
      sacc[st] = a;
    }

    // mask + online softmax
    float smv[4][4];
#pragma unroll
    for (int st = 0; st < 4; ++st) {
      const int jj = jt + st * 16 + lr;
#pragma unroll
      for (int r = 0; r < 4; ++r) {
        const int av = adj[(size_t)(qbase + lg * 4 + r) * 8192 + jj];
        smv[st][r] = (av != 0) ? sacc[st][r] : -1e9f;
      }
    }
    float p[4][4], alpha[4];
#pragma unroll
    for (int r = 0; r < 4; ++r) {
      float tm = fmaxf(fmaxf(smv[0][r], smv[1][r]), fmaxf(smv[2][r], smv[3][r]));
      tm = fmaxf(tm, __shfl_xor(tm, 1));
      tm = fmaxf(tm, __shfl_xor(tm, 2));
      tm = fmaxf(tm, __shfl_xor(tm, 4));
      tm = fmaxf(tm, __shfl_xor(tm, 8));
      const float mnew = fmaxf(mrow[r], tm);
      alpha[r] = exp2f((mrow[r] - mnew) * L2E);
      mrow[r] = mnew;
      float ps = 0.f;
#pragma unroll
      for (int st = 0; st < 4; ++st) {
        const float pv = exp2f((smv[st][r] - mnew) * L2E);
        p[st][r] = pv;
        ps += pv;
      }
      lrow[r] = lrow[r] * alpha[r] + ps;
    }
#pragma unroll
    for (int n = 0; n < 8; ++n) {
#pragma unroll
      for (int r = 0; r < 4; ++r) accO[n][r] *= alpha[r];
    }

    // P -> per-wave LDS (bf16), then read as A-frags
    __bf16* pw = &Plds[w][0];
#pragma unroll
    for (int st = 0; st < 4; ++st)
#pragma unroll
      for (int r = 0; r < 4; ++r)
        pw[(lg * 4 + r) * 72 + st * 16 + lr] = (__bf16)p[st][r];
    bf16x8 pf[2];
#pragma unroll
    for (int ks = 0; ks < 2; ++ks)
      pf[ks] = *reinterpret_cast<const bf16x8*>(&pw[lr * 72 + ks * 32 + lg * 8]);

    // O += P V
#pragma unroll
    for (int n = 0; n < 8; ++n) {
      const int dl = n * 16 + lr;
#pragma unroll
      for (int ks = 0; ks < 2; ++ks) {
        const bf16x8 vf = *reinterpret_cast<const bf16x8*>(
            &Vlds[dl * 64 + (((ks * 4 + lg) ^ (dl & 7)) * 8)]);
        accO[n] = __builtin_amdgcn_mfma_f32_16x16x32_bf16(pf[ks], vf, accO[n], 0, 0, 0);
      }
    }
    __syncthreads();
  }

  // write partials
#pragma unroll
  for (int r = 0; r < 4; ++r) {
    float ls = lrow[r];
    ls += __shfl_xor(ls, 1); ls += __shfl_xor(ls, 2);
    ls += __shfl_xor(ls, 4); ls += __shfl_xor(ls, 8);
    if (lr == 0) {
      const int qrow = qbase + lg * 4 + r;
      Marr[split * 8192 + qrow] = mrow[r];
      Larr[split * 8192 + qrow] = ls;
    }
  }
#pragma unroll
  for (int n = 0; n < 8; ++n)
#pragma unroll
    for (int r = 0; r < 4; ++r) {
      const int qrow = qbase + lg * 4 + r;
      Opart[(size_t)(split * 8192 + qrow) * 128 + n * 16 + lr] = accO[n][r];
    }
}

__global__ void combine_kernel(const float* __restrict__ Opart, const float* __restrict__ Marr,
                               const float* __restrict__ Larr, float* __restrict__ ctx) {
  const int id = blockIdx.x * 256 + threadIdx.x;  // 8192*32
  const int m = id >> 5, d4 = (id & 31) * 4;
  const float m0 = Marr[m], m1 = Marr[8192 + m], m2 = Marr[16384 + m], m3 = Marr[24576 + m];
  const float ms = fmaxf(fmaxf(m0, m1), fmaxf(m2, m3));
  const float w0 = exp2f((m0 - ms) * L2E), w1 = exp2f((m1 - ms) * L2E);
  const float w2 = exp2f((m2 - ms) * L2E), w3 = exp2f((m3 - ms) * L2E);
  const float den = w0 * Larr[m] + w1 * Larr[8192 + m] + w2 * Larr[16384 + m] + w3 * Larr[24576 + m];
  const float4 o0 = *reinterpret_cast<const float4*>(&Opart[(size_t)m * 128 + d4]);
  const float4 o1 = *reinterpret_cast<const float4*>(&Opart[(size_t)(8192 + m) * 128 + d4]);
  const float4 o2 = *reinterpret_cast<const float4*>(&Opart[(size_t)(16384 + m) * 128 + d4]);
  const float4 o3 = *reinterpret_cast<const float4*>(&Opart[(size_t)(24576 + m) * 128 + d4]);
  const float inv = 1.f / den;
  float4 r;
  r.x = (w0 * o0.x + w1 * o1.x + w2 * o2.x + w3 * o3.x) * inv;
  r.y = (w0 * o0.y + w1 * o1.y + w2 * o2.y + w3 * o3.y) * inv;
  r.z = (w0 * o0.z + w1 * o1.z + w2 * o2.z + w3 * o3.z) * inv;
  r.w = (w0 * o0.w + w1 * o1.w + w2 * o2.w + w3 * o3.w) * inv;
  *reinterpret_cast<float4*>(&ctx[(size_t)m * 128 + d4]) = r;
}

// q_values = [new_h | swarm] @ fcq_w^T + fcq_b  (N_ACT=5, K=256)
__global__ void fcq_kernel(const float* __restrict__ newh, const float* __restrict__ swarm,
                           const float* __restrict__ fw, const float* __restrict__ fb,
                           float* __restrict__ qout) {
  const int id = blockIdx.x * 256 + threadIdx.x;  // 40960
  const int row = id / 5, a = id - row * 5;
  const float4* x0 = reinterpret_cast<const float4*>(newh + (size_t)row * 128);
  const float4* x1 = reinterpret_cast<const float4*>(swarm + (size_t)row * 128);
  const float4* wv = reinterpret_cast<const float4*>(fw + a * 256);
  float acc = fb[a];
#pragma unroll
  for (int i = 0; i < 32; ++i) {
    const float4 x = x0[i], ww = wv[i];
    acc += x.x * ww.x + x.y * ww.y + x.z * ww.z + x.w * ww.w;
  }
#pragma unroll
  for (int i = 0; i < 32; ++i) {
    const float4 x = x1[i], ww = wv[32 + i];
    acc += x.x * ww.x + x.y * ww.y + x.z * ww.z + x.w * ww.w;
  }
  qout[id] = acc;
}

// ---------------------------------------------------------------------------
extern "C" void kernel_launch(void* const* d_in, const int* in_sizes, int n_in,
                              void* d_out, int out_size, void* d_ws, size_t ws_size,
                              hipStream_t stream) {
  const float* img    = (const float*)d_in[0];
  const int*   adj    = (const int*)d_in[1];
  const int*   cid    = (const int*)d_in[2];
  const float* hidden = (const float*)d_in[3];
  const float* w1  = (const float*)d_in[4];  const float* b1  = (const float*)d_in[5];
  const float* w2  = (const float*)d_in[6];  const float* b2  = (const float*)d_in[7];
  const float* fcw = (const float*)d_in[8];  const float* fcb = (const float*)d_in[9];
  const float* emb = (const float*)d_in[10];
  const float* wih = (const float*)d_in[11]; const float* whh = (const float*)d_in[12];
  const float* bih = (const float*)d_in[13]; const float* bhh = (const float*)d_in[14];
  const float* wq  = (const float*)d_in[15]; const float* wqb = (const float*)d_in[16];
  const float* wk  = (const float*)d_in[17]; const float* wkb = (const float*)d_in[18];
  const float* wv  = (const float*)d_in[19]; const float* wvb = (const float*)d_in[20];
  const float* wo  = (const float*)d_in[21]; const float* wob = (const float*)d_in[22];
  const float* fqw = (const float*)d_in[23]; const float* fqb = (const float*)d_in[24];

  float* out  = (float*)d_out;
  float* qout = out;                 // [8192][5]
  float* newh = out + 8192 * 5;      // [8192][128] fp32 output region, also used as tensor

  char* ws = (char*)d_ws;
  // region map (overlays commented with lifetimes)
  float* flat  = (float*)(ws + 0);          // 67.1MB  live: conv -> fc_vis
  float* gi    = (float*)(ws + 0);          // 12.6MB  live: gemm4 -> gates
  float* gh    = (float*)(ws + 12582912);   // 12.6MB
  float* Qf    = (float*)(ws + 25165824);   // 4.2MB x3
  float* Kf    = (float*)(ws + 29360128);
  float* Vf    = (float*)(ws + 33554432);
  __bf16* Qb   = (__bf16*)(ws + 37748736);  // 2MB x3
  __bf16* Kb   = (__bf16*)(ws + 39845888);
  __bf16* Vt   = (__bf16*)(ws + 41943040);
  float* Opart = (float*)(ws + 44040192);   // 16.8MB
  float* Marr  = (float*)(ws + 60817408);   // 128KB
  float* Larr  = (float*)(ws + 60948480);   // 128KB
  float* ctx   = (float*)(ws + 61079552);   // 4.2MB
  float* swarm = (float*)(ws + 0);          // reuse gi (dead after gates)
  float* feat  = (float*)(ws + 67108864);   // 4.7MB  live: fc_vis -> gemm4

  conv_fused<<<8192, 256, 0, stream>>>(img, w1, b1, w2, b2, flat);
  gemm_nt<1><<<dim3(256, 1), 256, 0, stream>>>(flat, fcw, fcb, feat, 8192, 128, 2048, 2048, 2048, 144);
  embed_fill<<<512, 256, 0, stream>>>(cid, emb, feat);
  gemm_nt<0><<<dim3(256, 3), 256, 0, stream>>>(feat, wih, bih, gi, 8192, 384, 144, 144, 144, 384);
  gemm_nt<0><<<dim3(256, 3), 256, 0, stream>>>(hidden, whh, bhh, gh, 8192, 384, 128, 128, 128, 384);
  gru_gates<<<4096, 256, 0, stream>>>(gi, gh, hidden, newh);
  gemm_nt<0><<<dim3(256, 1), 256, 0, stream>>>(newh, wq, wqb, Qf, 8192, 128, 128, 128, 128, 128);
  gemm_nt<0><<<dim3(256, 1), 256, 0, stream>>>(newh, wk, wkb, Kf, 8192, 128, 128, 128, 128, 128);
  gemm_nt<0><<<dim3(256, 1), 256, 0, stream>>>(newh, wv, wvb, Vf, 8192, 128, 128, 128, 128, 128);
  pack_qkv<<<128, 256, 0, stream>>>(Qf, Kf, Vf, Qb, Kb, Vt);
  flash_attn<<<dim3(128, 4), 256, 0, stream>>>(Qb, Kb, Vt, adj, Opart, Marr, Larr);
  combine_kernel<<<1024, 256, 0, stream>>>(Opart, Marr, Larr, ctx);
  gemm_nt<0><<<dim3(256, 1), 256, 0, stream>>>(ctx, wo, wob, swarm, 8192, 128, 128, 128, 128, 128);
  fcq_kernel<<<160, 256, 0, stream>>>(newh, swarm, fqw, fqb, qout);
}

// Round 7
// 1042.160 us; speedup vs baseline: 1.0703x; 1.0703x over previous
//
#include <hip/hip_runtime.h>

typedef __bf16 bf16x8 __attribute__((ext_vector_type(8)));
typedef float f32x4 __attribute__((ext_vector_type(4)));

#define L2E 1.4426950408889634f

// ---------------------------------------------------------------------------
// Fused conv1(5x5,s2)+ReLU -> conv2(3x3,s2)+ReLU per image. One block/image.
// img [3][40][40] -> c1 [16][18][18] -> flat out [2048] (=[32][8][8])
// Row-sliding register window + per-ic weight chunks from global (L1-resident)
// => no spills, LDS 39.9KB => 4 blocks/CU.
// ---------------------------------------------------------------------------
__global__ __launch_bounds__(256, 4) void conv_fused(
    const float* __restrict__ img, const float* __restrict__ w1, const float* __restrict__ b1,
    const float* __restrict__ w2, const float* __restrict__ b2, float* __restrict__ flat) {
  __shared__ float simg[4800];  // 3*40*40; reused as sc2[2048] after conv1
  __shared__ float sc1[5184];   // 16*18*18
  const int n = blockIdx.x, t = threadIdx.x;
  const float* ib = img + (size_t)n * 4800;
  for (int i = t; i < 4800; i += 256) simg[i] = ib[i];
  __syncthreads();

  // ---- conv1: thread -> oc pair (oc, oc+8), oc=t&7; 32 q-threads over 81 quads
  {
    const int oc = t & 7, qslot = t >> 3;
    float acc[3][2][4];
    const float bA = b1[oc], bB = b1[oc + 8];
#pragma unroll
    for (int qi = 0; qi < 3; ++qi)
#pragma unroll
      for (int j = 0; j < 4; ++j) { acc[qi][0][j] = bA; acc[qi][1][j] = bB; }
#pragma unroll
    for (int ic = 0; ic < 3; ++ic) {
      float wA[25], wB[25];
      const float* wpA = w1 + oc * 75 + ic * 25;
      const float* wpB = w1 + (oc + 8) * 75 + ic * 25;
#pragma unroll
      for (int i = 0; i < 25; ++i) { wA[i] = wpA[i]; wB[i] = wpB[i]; }
#pragma unroll
      for (int qi = 0; qi < 3; ++qi) {
        const int q = qslot + qi * 32;
        if (q < 81) {
          const int qy = q / 9, qx = q - qy * 9;
          const int base = ic * 1600 + qy * 160 + qx * 4;
#pragma unroll
          for (int row = 0; row < 7; ++row) {
            const float* rp = &simg[base + row * 40];
            const float4 v0 = *(const float4*)rp;
            const float2 v1 = *(const float2*)(rp + 4);
            float rr[7];
            rr[0] = v0.x; rr[1] = v0.y; rr[2] = v0.z; rr[3] = v0.w;
            rr[4] = v1.x; rr[5] = v1.y; rr[6] = rp[6];
            if (row < 5) {
#pragma unroll
              for (int kx = 0; kx < 5; ++kx) {
                const float wa = wA[row * 5 + kx], wb = wB[row * 5 + kx];
                acc[qi][0][0] = fmaf(rr[kx], wa, acc[qi][0][0]);
                acc[qi][0][1] = fmaf(rr[kx + 2], wa, acc[qi][0][1]);
                acc[qi][1][0] = fmaf(rr[kx], wb, acc[qi][1][0]);
                acc[qi][1][1] = fmaf(rr[kx + 2], wb, acc[qi][1][1]);
              }
            }
            if (row >= 2) {
#pragma unroll
              for (int kx = 0; kx < 5; ++kx) {
                const float wa = wA[(row - 2) * 5 + kx], wb = wB[(row - 2) * 5 + kx];
                acc[qi][0][2] = fmaf(rr[kx], wa, acc[qi][0][2]);
                acc[qi][0][3] = fmaf(rr[kx + 2], wa, acc[qi][0][3]);
                acc[qi][1][2] = fmaf(rr[kx], wb, acc[qi][1][2]);
                acc[qi][1][3] = fmaf(rr[kx + 2], wb, acc[qi][1][3]);
              }
            }
          }
        }
      }
    }
#pragma unroll
    for (int qi = 0; qi < 3; ++qi) {
      const int q = qslot + qi * 32;
      if (q < 81) {
        const int qy = q / 9, qx = q - qy * 9;
#pragma unroll
        for (int p = 0; p < 2; ++p) {
          const int o = (oc + p * 8) * 324 + qy * 36 + qx * 2;
          float2 top, bot;
          top.x = fmaxf(acc[qi][p][0], 0.f); top.y = fmaxf(acc[qi][p][1], 0.f);
          bot.x = fmaxf(acc[qi][p][2], 0.f); bot.y = fmaxf(acc[qi][p][3], 0.f);
          *(float2*)&sc1[o] = top;
          *(float2*)&sc1[o + 18] = bot;
        }
      }
    }
  }
  __syncthreads();  // sc1 visible; simg reads done

  // ---- conv2: thread -> oc pair (oc, oc+16), oc=t&15; 16 q-threads, 1 quad each
  float* sc2 = simg;
  {
    const int oc = t & 15, qslot = t >> 4;
    const int qy = qslot >> 2, qx = qslot & 3;
    float accA[4], accB[4];
    const float bA = b2[oc], bB = b2[oc + 16];
#pragma unroll
    for (int j = 0; j < 4; ++j) { accA[j] = bA; accB[j] = bB; }
#pragma unroll
    for (int ic = 0; ic < 16; ++ic) {
      float wA[9], wB[9];
      const float* wpA = w2 + oc * 144 + ic * 9;
      const float* wpB = w2 + (oc + 16) * 144 + ic * 9;
#pragma unroll
      for (int i = 0; i < 9; ++i) { wA[i] = wpA[i]; wB[i] = wpB[i]; }
      const int base = ic * 324 + qy * 72 + qx * 4;
#pragma unroll
      for (int row = 0; row < 5; ++row) {
        const float* rp = &sc1[base + row * 18];
        const float2 v0 = *(const float2*)rp;
        const float2 v1 = *(const float2*)(rp + 2);
        float rr[5];
        rr[0] = v0.x; rr[1] = v0.y; rr[2] = v1.x; rr[3] = v1.y; rr[4] = rp[4];
        if (row < 3) {
#pragma unroll
          for (int kx = 0; kx < 3; ++kx) {
            const float wa = wA[row * 3 + kx], wb = wB[row * 3 + kx];
            accA[0] = fmaf(rr[kx], wa, accA[0]);
            accA[1] = fmaf(rr[kx + 2], wa, accA[1]);
            accB[0] = fmaf(rr[kx], wb, accB[0]);
            accB[1] = fmaf(rr[kx + 2], wb, accB[1]);
          }
        }
        if (row >= 2) {
#pragma unroll
          for (int kx = 0; kx < 3; ++kx) {
            const float wa = wA[(row - 2) * 3 + kx], wb = wB[(row - 2) * 3 + kx];
            accA[2] = fmaf(rr[kx], wa, accA[2]);
            accA[3] = fmaf(rr[kx + 2], wa, accA[3]);
            accB[2] = fmaf(rr[kx], wb, accB[2]);
            accB[3] = fmaf(rr[kx + 2], wb, accB[3]);
          }
        }
      }
    }
    const int oA = oc * 64 + qy * 16 + qx * 2;
    const int oB = (oc + 16) * 64 + qy * 16 + qx * 2;
    sc2[oA] = fmaxf(accA[0], 0.f); sc2[oA + 1] = fmaxf(accA[1], 0.f);
    sc2[oA + 8] = fmaxf(accA[2], 0.f); sc2[oA + 9] = fmaxf(accA[3], 0.f);
    sc2[oB] = fmaxf(accB[0], 0.f); sc2[oB + 1] = fmaxf(accB[1], 0.f);
    sc2[oB + 8] = fmaxf(accB[2], 0.f); sc2[oB + 9] = fmaxf(accB[3], 0.f);
  }
  __syncthreads();
  float* ob = flat + (size_t)n * 2048;
  for (int i = t; i < 2048; i += 256) ob[i] = sc2[i];
}

// ---------------------------------------------------------------------------
// fp32 GEMM: C[m][n] = epi(sum_k A[m*lda+k]*W[n*ldw+k] + bias[n])
// tile 32(M) x 64(N), K-step 32, double-buffered LDS. grid (M/32, N/64).
// EPI: 0 none, 1 relu
// ---------------------------------------------------------------------------
template <int EPI>
__global__ __launch_bounds__(256) void gemm_nt(
    const float* __restrict__ A, const float* __restrict__ W, const float* __restrict__ bias,
    float* __restrict__ C, int M, int N, int K, int lda, int ldw, int ldc) {
  __shared__ float As[2][32][36];
  __shared__ float Ws[2][32][66];
  const int t = threadIdx.x;
  const int m0 = blockIdx.x * 32, n0 = blockIdx.y * 64;
  const int arow = t >> 3, ak = (t & 7) * 4;
  const int wrow = t >> 2, wk = (t & 3) * 8;
  const int tm = t >> 5, tn = t & 31;
  float acc[4][2] = {{0.f, 0.f}, {0.f, 0.f}, {0.f, 0.f}, {0.f, 0.f}};
  float4 av, wv0, wv1;

  auto load_g = [&](int k0) {
    av = float4{0.f, 0.f, 0.f, 0.f};
    wv0 = float4{0.f, 0.f, 0.f, 0.f};
    wv1 = float4{0.f, 0.f, 0.f, 0.f};
    if (k0 + ak < K) av = *(const float4*)&A[(size_t)(m0 + arow) * lda + k0 + ak];
    if (k0 + wk < K) wv0 = *(const float4*)&W[(size_t)(n0 + wrow) * ldw + k0 + wk];
    if (k0 + wk + 4 < K) wv1 = *(const float4*)&W[(size_t)(n0 + wrow) * ldw + k0 + wk + 4];
  };
  auto store_l = [&](int buf) {
    As[buf][ak + 0][arow] = av.x; As[buf][ak + 1][arow] = av.y;
    As[buf][ak + 2][arow] = av.z; As[buf][ak + 3][arow] = av.w;
    Ws[buf][wk + 0][wrow] = wv0.x; Ws[buf][wk + 1][wrow] = wv0.y;
    Ws[buf][wk + 2][wrow] = wv0.z; Ws[buf][wk + 3][wrow] = wv0.w;
    Ws[buf][wk + 4][wrow] = wv1.x; Ws[buf][wk + 5][wrow] = wv1.y;
    Ws[buf][wk + 6][wrow] = wv1.z; Ws[buf][wk + 7][wrow] = wv1.w;
  };
  auto compute = [&](int buf) {
#pragma unroll
    for (int kk = 0; kk < 32; ++kk) {
      const float4 a = *(const float4*)&As[buf][kk][tm * 4];
      const float2 b = *(const float2*)&Ws[buf][kk][tn * 2];
      acc[0][0] = fmaf(a.x, b.x, acc[0][0]); acc[0][1] = fmaf(a.x, b.y, acc[0][1]);
      acc[1][0] = fmaf(a.y, b.x, acc[1][0]); acc[1][1] = fmaf(a.y, b.y, acc[1][1]);
      acc[2][0] = fmaf(a.z, b.x, acc[2][0]); acc[2][1] = fmaf(a.z, b.y, acc[2][1]);
      acc[3][0] = fmaf(a.w, b.x, acc[3][0]); acc[3][1] = fmaf(a.w, b.y, acc[3][1]);
    }
  };

  load_g(0);
  store_l(0);
  __syncthreads();
  int cur = 0;
  for (int k0 = 32; k0 < K; k0 += 32) {
    load_g(k0);
    compute(cur);
    __syncthreads();
    store_l(cur ^ 1);
    __syncthreads();
    cur ^= 1;
  }
  compute(cur);

  const float b0 = bias[n0 + tn * 2], b1 = bias[n0 + tn * 2 + 1];
#pragma unroll
  for (int i = 0; i < 4; ++i) {
    float r0 = acc[i][0] + b0, r1 = acc[i][1] + b1;
    if (EPI == 1) { r0 = fmaxf(r0, 0.f); r1 = fmaxf(r1, 0.f); }
    float2 o; o.x = r0; o.y = r1;
    *(float2*)&C[(size_t)(m0 + tm * 4 + i) * ldc + n0 + tn * 2] = o;
  }
}

// ---------------------------------------------------------------------------
__global__ void embed_fill(const int* __restrict__ cid, const float* __restrict__ emb,
                           float* __restrict__ feat) {
  const int id = blockIdx.x * 256 + threadIdx.x;  // 8192*16
  const int n = id >> 4, e = id & 15;
  feat[n * 144 + 128 + e] = emb[cid[n] * 16 + e];
}

__global__ void gru_gates(const float* __restrict__ gi, const float* __restrict__ gh,
                          const float* __restrict__ h, float* __restrict__ nh) {
  const int id = blockIdx.x * 256 + threadIdx.x;  // 8192*128
  const int n = id >> 7, j = id & 127;
  const int b = n * 384 + j;
  const float r = 1.f / (1.f + __expf(-(gi[b] + gh[b])));
  const float z = 1.f / (1.f + __expf(-(gi[b + 128] + gh[b + 128])));
  const float nn = tanhf(gi[b + 256] + r * gh[b + 256]);
  nh[id] = (1.f - z) * nn + z * h[id];
}

// Qf,Kf,Vf fp32 [8192][128] -> Qb (scaled) bf16, Kb bf16 row-major, Vt bf16 [128][8192]
__global__ __launch_bounds__(256) void pack_qkv(
    const float* __restrict__ Qf, const float* __restrict__ Kf, const float* __restrict__ Vf,
    __bf16* __restrict__ Qb, __bf16* __restrict__ Kb, __bf16* __restrict__ Vt) {
  __shared__ float sv[64][132];
  const int t = threadIdx.x;
  const int m0 = blockIdx.x * 64;
  for (int i = t; i < 8192; i += 256) {
    const int mm = i >> 7, c = i & 127;
    const int g = (m0 + mm) * 128 + c;
    Qb[g] = (__bf16)(Qf[g] * 0.08838834764831845f);  // 1/sqrt(128)
    Kb[g] = (__bf16)Kf[g];
    sv[mm][c] = Vf[g];
  }
  __syncthreads();
  const int d = t >> 1, mh = (t & 1) * 32;
#pragma unroll
  for (int g8 = 0; g8 < 4; ++g8) {
    bf16x8 v;
#pragma unroll
    for (int j = 0; j < 8; ++j) v[j] = (__bf16)sv[mh + g8 * 8 + j][d];
    *reinterpret_cast<bf16x8*>(&Vt[(size_t)d * 8192 + m0 + mh + g8 * 8]) = v;
  }
}

// ---------------------------------------------------------------------------
// Flash attention, bf16 MFMA 16x16x32. Block = 4 waves, 64 q rows.
// grid (128 qblocks, 4 j-splits). Partials: Opart (unnormalized), Marr, Larr.
// ---------------------------------------------------------------------------
__global__ __launch_bounds__(256, 3) void flash_attn(
    const __bf16* __restrict__ Qb, const __bf16* __restrict__ Kb, const __bf16* __restrict__ Vt,
    const int* __restrict__ adj, float* __restrict__ Opart,
    float* __restrict__ Marr, float* __restrict__ Larr) {
  __shared__ __bf16 Klds[64 * 128];   // [j][k], xor-swizzled 16B chunks
  __shared__ __bf16 Vlds[128 * 64];   // [d][j], xor-swizzled
  __shared__ __bf16 Plds[4][16 * 72]; // per-wave P tile, row stride 72
  const int t = threadIdx.x;
  const int w = t >> 6, l = t & 63;
  const int lr = l & 15, lg = l >> 4;
  const int qbase = blockIdx.x * 64 + w * 16;
  const int split = blockIdx.y;

  bf16x8 qf[4];
#pragma unroll
  for (int kk = 0; kk < 4; ++kk)
    qf[kk] = *reinterpret_cast<const bf16x8*>(&Qb[(qbase + lr) * 128 + kk * 32 + lg * 8]);

  f32x4 accO[8];
#pragma unroll
  for (int n = 0; n < 8; ++n) accO[n] = f32x4{0.f, 0.f, 0.f, 0.f};
  float mrow[4] = {-1e9f, -1e9f, -1e9f, -1e9f};
  float lrow[4] = {0.f, 0.f, 0.f, 0.f};

  const int j0 = split * 2048, j1 = j0 + 2048;
  for (int jt = j0; jt < j1; jt += 64) {
    // stage K (64x128) and V (128x64) tiles, swizzle chunk ^= row&7
#pragma unroll
    for (int i = 0; i < 4; ++i) {
      const int idx = i * 256 + t;
      {
        const int row = idx >> 4, c = idx & 15;
        const uint4 v = *reinterpret_cast<const uint4*>(&Kb[(size_t)(jt + row) * 128 + c * 8]);
        *reinterpret_cast<uint4*>(&Klds[row * 128 + ((c ^ (row & 7)) * 8)]) = v;
      }
      {
        const int d = idx >> 3, c = idx & 7;
        const uint4 v = *reinterpret_cast<const uint4*>(&Vt[(size_t)d * 8192 + jt + c * 8]);
        *reinterpret_cast<uint4*>(&Vlds[d * 64 + ((c ^ (d & 7)) * 8)]) = v;
      }
    }
    __syncthreads();

    // S = Q K^T  (rows=q via C-layout, cols=j)
    f32x4 sacc[4];
#pragma unroll
    for (int st = 0; st < 4; ++st) {
      f32x4 a = f32x4{0.f, 0.f, 0.f, 0.f};
      const int jl = st * 16 + lr;
#pragma unroll
      for (int kk = 0; kk < 4; ++kk) {
        const bf16x8 kf = *reinterpret_cast<const bf16x8*>(
            &Klds[jl * 128 + (((kk * 4 + lg) ^ (jl & 7)) * 8)]);
        a = __builtin_amdgcn_mfma_f32_16x16x32_bf16(qf[kk], kf, a, 0, 0, 0);
      }
      sacc[st] = a;
    }

    // mask + online softmax (in-place pv overlay: masked score -> p)
    float pv[4][4];
#pragma unroll
    for (int st = 0; st < 4; ++st) {
      const int jj = jt + st * 16 + lr;
#pragma unroll
      for (int r = 0; r < 4; ++r) {
        const int av = adj[(size_t)(qbase + lg * 4 + r) * 8192 + jj];
        pv[st][r] = (av != 0) ? sacc[st][r] : -1e9f;
      }
    }
    float alpha[4];
#pragma unroll
    for (int r = 0; r < 4; ++r) {
      float tm = fmaxf(fmaxf(pv[0][r], pv[1][r]), fmaxf(pv[2][r], pv[3][r]));
      tm = fmaxf(tm, __shfl_xor(tm, 1));
      tm = fmaxf(tm, __shfl_xor(tm, 2));
      tm = fmaxf(tm, __shfl_xor(tm, 4));
      tm = fmaxf(tm, __shfl_xor(tm, 8));
      const float mnew = fmaxf(mrow[r], tm);
      alpha[r] = exp2f((mrow[r] - mnew) * L2E);
      mrow[r] = mnew;
      float ps = 0.f;
#pragma unroll
      for (int st = 0; st < 4; ++st) {
        const float e = exp2f((pv[st][r] - mnew) * L2E);
        pv[st][r] = e;
        ps += e;
      }
      lrow[r] = lrow[r] * alpha[r] + ps;
    }
#pragma unroll
    for (int n = 0; n < 8; ++n) {
#pragma unroll
      for (int r = 0; r < 4; ++r) accO[n][r] *= alpha[r];
    }

    // P -> per-wave LDS (bf16), then read as A-frags
    __bf16* pw = &Plds[w][0];
#pragma unroll
    for (int st = 0; st < 4; ++st)
#pragma unroll
      for (int r = 0; r < 4; ++r)
        pw[(lg * 4 + r) * 72 + st * 16 + lr] = (__bf16)pv[st][r];
    bf16x8 pf[2];
#pragma unroll
    for (int ks = 0; ks < 2; ++ks)
      pf[ks] = *reinterpret_cast<const bf16x8*>(&pw[lr * 72 + ks * 32 + lg * 8]);

    // O += P V
#pragma unroll
    for (int n = 0; n < 8; ++n) {
      const int dl = n * 16 + lr;
#pragma unroll
      for (int ks = 0; ks < 2; ++ks) {
        const bf16x8 vf = *reinterpret_cast<const bf16x8*>(
            &Vlds[dl * 64 + (((ks * 4 + lg) ^ (dl & 7)) * 8)]);
        accO[n] = __builtin_amdgcn_mfma_f32_16x16x32_bf16(pf[ks], vf, accO[n], 0, 0, 0);
      }
    }
    __syncthreads();
  }

  // write partials
#pragma unroll
  for (int r = 0; r < 4; ++r) {
    float ls = lrow[r];
    ls += __shfl_xor(ls, 1); ls += __shfl_xor(ls, 2);
    ls += __shfl_xor(ls, 4); ls += __shfl_xor(ls, 8);
    if (lr == 0) {
      const int qrow = qbase + lg * 4 + r;
      Marr[split * 8192 + qrow] = mrow[r];
      Larr[split * 8192 + qrow] = ls;
    }
  }
#pragma unroll
  for (int n = 0; n < 8; ++n)
#pragma unroll
    for (int r = 0; r < 4; ++r) {
      const int qrow = qbase + lg * 4 + r;
      Opart[(size_t)(split * 8192 + qrow) * 128 + n * 16 + lr] = accO[n][r];
    }
}

__global__ void combine_kernel(const float* __restrict__ Opart, const float* __restrict__ Marr,
                               const float* __restrict__ Larr, float* __restrict__ ctx) {
  const int id = blockIdx.x * 256 + threadIdx.x;  // 8192*32
  const int m = id >> 5, d4 = (id & 31) * 4;
  const float m0 = Marr[m], m1 = Marr[8192 + m], m2 = Marr[16384 + m], m3 = Marr[24576 + m];
  const float ms = fmaxf(fmaxf(m0, m1), fmaxf(m2, m3));
  const float w0 = exp2f((m0 - ms) * L2E), w1 = exp2f((m1 - ms) * L2E);
  const float w2 = exp2f((m2 - ms) * L2E), w3 = exp2f((m3 - ms) * L2E);
  const float den = w0 * Larr[m] + w1 * Larr[8192 + m] + w2 * Larr[16384 + m] + w3 * Larr[24576 + m];
  const float4 o0 = *reinterpret_cast<const float4*>(&Opart[(size_t)m * 128 + d4]);
  const float4 o1 = *reinterpret_cast<const float4*>(&Opart[(size_t)(8192 + m) * 128 + d4]);
  const float4 o2 = *reinterpret_cast<const float4*>(&Opart[(size_t)(16384 + m) * 128 + d4]);
  const float4 o3 = *reinterpret_cast<const float4*>(&Opart[(size_t)(24576 + m) * 128 + d4]);
  const float inv = 1.f / den;
  float4 r;
  r.x = (w0 * o0.x + w1 * o1.x + w2 * o2.x + w3 * o3.x) * inv;
  r.y = (w0 * o0.y + w1 * o1.y + w2 * o2.y + w3 * o3.y) * inv;
  r.z = (w0 * o0.z + w1 * o1.z + w2 * o2.z + w3 * o3.z) * inv;
  r.w = (w0 * o0.w + w1 * o1.w + w2 * o2.w + w3 * o3.w) * inv;
  *reinterpret_cast<float4*>(&ctx[(size_t)m * 128 + d4]) = r;
}

// q_values = [new_h | swarm] @ fcq_w^T + fcq_b  (N_ACT=5, K=256)
__global__ void fcq_kernel(const float* __restrict__ newh, const float* __restrict__ swarm,
                           const float* __restrict__ fw, const float* __restrict__ fb,
                           float* __restrict__ qout) {
  const int id = blockIdx.x * 256 + threadIdx.x;  // 40960
  const int row = id / 5, a = id - row * 5;
  const float4* x0 = reinterpret_cast<const float4*>(newh + (size_t)row * 128);
  const float4* x1 = reinterpret_cast<const float4*>(swarm + (size_t)row * 128);
  const float4* wv = reinterpret_cast<const float4*>(fw + a * 256);
  float acc = fb[a];
#pragma unroll
  for (int i = 0; i < 32; ++i) {
    const float4 x = x0[i], ww = wv[i];
    acc += x.x * ww.x + x.y * ww.y + x.z * ww.z + x.w * ww.w;
  }
#pragma unroll
  for (int i = 0; i < 32; ++i) {
    const float4 x = x1[i], ww = wv[32 + i];
    acc += x.x * ww.x + x.y * ww.y + x.z * ww.z + x.w * ww.w;
  }
  qout[id] = acc;
}

// ---------------------------------------------------------------------------
extern "C" void kernel_launch(void* const* d_in, const int* in_sizes, int n_in,
                              void* d_out, int out_size, void* d_ws, size_t ws_size,
                              hipStream_t stream) {
  const float* img    = (const float*)d_in[0];
  const int*   adj    = (const int*)d_in[1];
  const int*   cid    = (const int*)d_in[2];
  const float* hidden = (const float*)d_in[3];
  const float* w1  = (const float*)d_in[4];  const float* b1  = (const float*)d_in[5];
  const float* w2  = (const float*)d_in[6];  const float* b2  = (const float*)d_in[7];
  const float* fcw = (const float*)d_in[8];  const float* fcb = (const float*)d_in[9];
  const float* emb = (const float*)d_in[10];
  const float* wih = (const float*)d_in[11]; const float* whh = (const float*)d_in[12];
  const float* bih = (const float*)d_in[13]; const float* bhh = (const float*)d_in[14];
  const float* wq  = (const float*)d_in[15]; const float* wqb = (const float*)d_in[16];
  const float* wk  = (const float*)d_in[17]; const float* wkb = (const float*)d_in[18];
  const float* wv  = (const float*)d_in[19]; const float* wvb = (const float*)d_in[20];
  const float* wo  = (const float*)d_in[21]; const float* wob = (const float*)d_in[22];
  const float* fqw = (const float*)d_in[23]; const float* fqb = (const float*)d_in[24];

  float* out  = (float*)d_out;
  float* qout = out;                 // [8192][5]
  float* newh = out + 8192 * 5;      // [8192][128]

  char* ws = (char*)d_ws;
  float* flat  = (float*)(ws + 0);          // 67.1MB  live: conv -> fc_vis
  float* gi    = (float*)(ws + 0);          // 12.6MB  live: gemm -> gates
  float* gh    = (float*)(ws + 12582912);   // 12.6MB
  float* Qf    = (float*)(ws + 25165824);   // 4.2MB x3
  float* Kf    = (float*)(ws + 29360128);
  float* Vf    = (float*)(ws + 33554432);
  __bf16* Qb   = (__bf16*)(ws + 37748736);  // 2MB x3
  __bf16* Kb   = (__bf16*)(ws + 39845888);
  __bf16* Vt   = (__bf16*)(ws + 41943040);
  float* Opart = (float*)(ws + 44040192);   // 16.8MB
  float* Marr  = (float*)(ws + 60817408);   // 128KB
  float* Larr  = (float*)(ws + 60948480);   // 128KB
  float* ctx   = (float*)(ws + 61079552);   // 4.2MB
  float* swarm = (float*)(ws + 0);          // reuse gi (dead after gates)
  float* feat  = (float*)(ws + 67108864);   // 4.7MB  live: fc_vis -> gi gemm

  conv_fused<<<8192, 256, 0, stream>>>(img, w1, b1, w2, b2, flat);
  gemm_nt<1><<<dim3(256, 2), 256, 0, stream>>>(flat, fcw, fcb, feat, 8192, 128, 2048, 2048, 2048, 144);
  embed_fill<<<512, 256, 0, stream>>>(cid, emb, feat);
  gemm_nt<0><<<dim3(256, 6), 256, 0, stream>>>(feat, wih, bih, gi, 8192, 384, 144, 144, 144, 384);
  gemm_nt<0><<<dim3(256, 6), 256, 0, stream>>>(hidden, whh, bhh, gh, 8192, 384, 128, 128, 128, 384);
  gru_gates<<<4096, 256, 0, stream>>>(gi, gh, hidden, newh);
  gemm_nt<0><<<dim3(256, 2), 256, 0, stream>>>(newh, wq, wqb, Qf, 8192, 128, 128, 128, 128, 128);
  gemm_nt<0><<<dim3(256, 2), 256, 0, stream>>>(newh, wk, wkb, Kf, 8192, 128, 128, 128, 128, 128);
  gemm_nt<0><<<dim3(256, 2), 256, 0, stream>>>(newh, wv, wvb, Vf, 8192, 128, 128, 128, 128, 128);
  pack_qkv<<<128, 256, 0, stream>>>(Qf, Kf, Vf, Qb, Kb, Vt);
  flash_attn<<<dim3(128, 4), 256, 0, stream>>>(Qb, Kb, Vt, adj, Opart, Marr, Larr);
  combine_kernel<<<1024, 256, 0, stream>>>(Opart, Marr, Larr, ctx);
  gemm_nt<0><<<dim3(256, 2), 256, 0, stream>>>(ctx, wo, wob, swarm, 8192, 128, 128, 128, 128, 128);
  fcq_kernel<<<160, 256, 0, stream>>>(newh, swarm, fqw, fqb, qout);
}